// Round 17
// baseline (353.209 us; speedup 1.0000x reference)
//
#include <hip/hip_runtime.h>
#include <math.h>
#include <stdint.h>

#define N_NODES 100000
#define EMB_DIM 128
#define N_EDGES 600000
#define SCAN_BLOCKS ((N_NODES + 255) / 256)   // 391

// f32 -> bf16 (round-to-nearest-even), returns low 16 bits
__device__ __forceinline__ unsigned int f2b(float f) {
    unsigned int b = __float_as_uint(f);
    return (b + 0x7FFFu + ((b >> 16) & 1u)) >> 16;
}

__global__ void k_init(float* __restrict__ sum_out, int* __restrict__ deg) {
    int i = blockIdx.x * blockDim.x + threadIdx.x;
    if (i < N_NODES) {
        sum_out[i] = 0.0f;
        deg[i]     = 0;
    }
}

// edge pass: pure target-degree histogram (1 int atomic/edge)
__global__ void k_edge(const int* __restrict__ to_, int* __restrict__ deg) {
    int e = blockIdx.x * blockDim.x + threadIdx.x;
    if (e >= N_EDGES) return;
    atomicAdd(&deg[to_[e]], 1);
}

// ---- hierarchical scan: deg -> row_ptr (exclusive prefix) ----
__global__ void k_scan1(const int* __restrict__ deg, int* __restrict__ local,
                        int* __restrict__ blockSums) {
    __shared__ int tmp[256];
    int t = threadIdx.x;
    int i = blockIdx.x * 256 + t;
    int v = (i < N_NODES) ? deg[i] : 0;
    tmp[t] = v;
    __syncthreads();
    for (int ofs = 1; ofs < 256; ofs <<= 1) {
        int add = (t >= ofs) ? tmp[t - ofs] : 0;
        __syncthreads();
        tmp[t] += add;
        __syncthreads();
    }
    if (i < N_NODES) local[i] = tmp[t] - v;
    if (t == 255) blockSums[blockIdx.x] = tmp[255];
}

__global__ void k_scan2(int* __restrict__ blockSums) {
    __shared__ int tmp[256];
    int t = threadIdx.x;
    int i0 = t * 2, i1 = t * 2 + 1;
    int a = (i0 < SCAN_BLOCKS) ? blockSums[i0] : 0;
    int b = (i1 < SCAN_BLOCKS) ? blockSums[i1] : 0;
    int s = a + b;
    tmp[t] = s;
    __syncthreads();
    for (int ofs = 1; ofs < 256; ofs <<= 1) {
        int add = (t >= ofs) ? tmp[t - ofs] : 0;
        __syncthreads();
        tmp[t] += add;
        __syncthreads();
    }
    int pre = tmp[t] - s;
    if (i0 < SCAN_BLOCKS) blockSums[i0] = pre;
    if (i1 < SCAN_BLOCKS) blockSums[i1] = pre + a;
}

__global__ void k_scan3(const int* __restrict__ local, const int* __restrict__ blockSums,
                        int* __restrict__ row_ptr, int* __restrict__ cursor) {
    int i = blockIdx.x * 256 + threadIdx.x;
    if (i < N_NODES) {
        int r = local[i] + blockSums[blockIdx.x];
        row_ptr[i] = r;
        cursor[i]  = r;
    }
    if (i == 0) row_ptr[N_NODES] = N_EDGES;
}

// scatter edges into CSR slots (single int2 store: {col, exp(attr) bits})
// + sum_out float atomic (moved here from k_edge; k_norm runs after this)
__global__ void k_fill(const int* __restrict__ from_, const int* __restrict__ to_,
                       const float* __restrict__ attr,
                       float* __restrict__ sum_out,
                       int* __restrict__ cursor, int2* __restrict__ cv) {
    int e = blockIdx.x * blockDim.x + threadIdx.x;
    if (e >= N_EDGES) return;
    int f = from_[e], t = to_[e];
    float ex = expf(attr[e]);
    atomicAdd(&sum_out[f], ex);
    int pos = atomicAdd(&cursor[t], 1);
    cv[pos] = make_int2(f, __float_as_int(ex));
}

// per-row: sum_in = contiguous segment sum; in-place normalize of cv.y
__global__ void k_norm(const int* __restrict__ row_ptr, int2* __restrict__ cv,
                       const float* __restrict__ sum_out) {
    int r = blockIdx.x * 256 + threadIdx.x;
    if (r >= N_NODES) return;
    int beg = row_ptr[r], end = row_ptr[r + 1];
    float s = 0.0f;
    for (int e = beg; e < end; ++e) s += __int_as_float(cv[e].y);
    for (int e = beg; e < end; ++e) {
        int2 c = cv[e];
        float v = __int_as_float(c.y) * rsqrtf(s * sum_out[c.x]);
        cv[e].y = __float_as_int(v);
    }
}

// convert f32 table -> bf16 table AND write the exact f32 emb0 copy to d_out
__global__ void k_cvt(const float* __restrict__ in, uint4* __restrict__ out,
                      float* __restrict__ out_emb0) {
    int i = blockIdx.x * 256 + threadIdx.x;
    const int total = N_NODES * EMB_DIM / 8;   // 1.6M
    if (i >= total) return;
    const float4* p = reinterpret_cast<const float4*>(in) + (size_t)i * 2;
    float4 a = p[0], b = p[1];
    uint4 q;
    q.x = f2b(a.x) | (f2b(a.y) << 16);
    q.y = f2b(a.z) | (f2b(a.w) << 16);
    q.z = f2b(b.x) | (f2b(b.y) << 16);
    q.w = f2b(b.z) | (f2b(b.w) << 16);
    out[i] = q;
    float4* o = reinterpret_cast<float4*>(out_emb0) + (size_t)i * 2;
    o[0] = a;
    o[1] = b;
}

#define UNPACK_FMA(q, v)                                      \
    s0 = fmaf(v, __uint_as_float((q).x << 16), s0);           \
    s1 = fmaf(v, __uint_as_float((q).x & 0xFFFF0000u), s1);   \
    s2 = fmaf(v, __uint_as_float((q).y << 16), s2);           \
    s3 = fmaf(v, __uint_as_float((q).y & 0xFFFF0000u), s3);   \
    s4 = fmaf(v, __uint_as_float((q).z << 16), s4);           \
    s5 = fmaf(v, __uint_as_float((q).z & 0xFFFF0000u), s5);   \
    s6 = fmaf(v, __uint_as_float((q).w << 16), s6);           \
    s7 = fmaf(v, __uint_as_float((q).w & 0xFFFF0000u), s7);

// SpMM over bf16 table: 16 lanes/row (4 rows/wave), one uint4 (8 bf16) per lane,
// unrolled x4 -> 16 concurrent gather chains per wave. f32 accumulation.
// Edge stream is int2 {col, val} -> one 8B load per edge.
// FINAL=0: dstb[row] = bf16(s)
// FINAL=1: out_acc = (emb0_f32 + e1b + e2b + s)*0.25
template<int FINAL>
__launch_bounds__(256)
__global__ void k_spmm(const int* __restrict__ row_ptr, const int2* __restrict__ cv,
                       const uint4* __restrict__ srcb, uint4* __restrict__ dstb,
                       const float* __restrict__ emb0,
                       const uint4* __restrict__ e1b, const uint4* __restrict__ e2b,
                       float* __restrict__ out_acc) {
    int gid = blockIdx.x * 256 + threadIdx.x;
    int row = gid >> 4;
    if (row >= N_NODES) return;
    int lane = threadIdx.x & 15;
    int beg = row_ptr[row], end = row_ptr[row + 1];
    float s0 = 0.f, s1 = 0.f, s2 = 0.f, s3 = 0.f, s4 = 0.f, s5 = 0.f, s6 = 0.f, s7 = 0.f;
    int e = beg;
    for (; e + 4 <= end; e += 4) {
        int2 ca = cv[e], cb = cv[e + 1], cc = cv[e + 2], cd = cv[e + 3];
        uint4 qa = srcb[(size_t)ca.x * 16 + lane];
        uint4 qb = srcb[(size_t)cb.x * 16 + lane];
        uint4 qc = srcb[(size_t)cc.x * 16 + lane];
        uint4 qd = srcb[(size_t)cd.x * 16 + lane];
        float v0 = __int_as_float(ca.y), v1 = __int_as_float(cb.y);
        float v2 = __int_as_float(cc.y), v3 = __int_as_float(cd.y);
        UNPACK_FMA(qa, v0)
        UNPACK_FMA(qb, v1)
        UNPACK_FMA(qc, v2)
        UNPACK_FMA(qd, v3)
    }
    for (; e < end; ++e) {
        int2 c = cv[e];
        float v = __int_as_float(c.y);
        uint4 q = srcb[(size_t)c.x * 16 + lane];
        UNPACK_FMA(q, v)
    }
    if (!FINAL) {
        uint4 q;
        q.x = f2b(s0) | (f2b(s1) << 16);
        q.y = f2b(s2) | (f2b(s3) << 16);
        q.z = f2b(s4) | (f2b(s5) << 16);
        q.w = f2b(s6) | (f2b(s7) << 16);
        dstb[(size_t)row * 16 + lane] = q;
    } else {
        size_t o = (size_t)row * EMB_DIM + lane * 8;
        float4 a0 = *reinterpret_cast<const float4*>(emb0 + o);
        float4 a1 = *reinterpret_cast<const float4*>(emb0 + o + 4);
        uint4 q1 = e1b[(size_t)row * 16 + lane];
        uint4 q2 = e2b[(size_t)row * 16 + lane];
        float4 r0, r1;
        r0.x = (a0.x + __uint_as_float(q1.x << 16)          + __uint_as_float(q2.x << 16)          + s0) * 0.25f;
        r0.y = (a0.y + __uint_as_float(q1.x & 0xFFFF0000u)  + __uint_as_float(q2.x & 0xFFFF0000u)  + s1) * 0.25f;
        r0.z = (a0.z + __uint_as_float(q1.y << 16)          + __uint_as_float(q2.y << 16)          + s2) * 0.25f;
        r0.w = (a0.w + __uint_as_float(q1.y & 0xFFFF0000u)  + __uint_as_float(q2.y & 0xFFFF0000u)  + s3) * 0.25f;
        r1.x = (a1.x + __uint_as_float(q1.z << 16)          + __uint_as_float(q2.z << 16)          + s4) * 0.25f;
        r1.y = (a1.y + __uint_as_float(q1.z & 0xFFFF0000u)  + __uint_as_float(q2.z & 0xFFFF0000u)  + s5) * 0.25f;
        r1.z = (a1.z + __uint_as_float(q1.w << 16)          + __uint_as_float(q2.w << 16)          + s6) * 0.25f;
        r1.w = (a1.w + __uint_as_float(q1.w & 0xFFFF0000u)  + __uint_as_float(q2.w & 0xFFFF0000u)  + s7) * 0.25f;
        *reinterpret_cast<float4*>(out_acc + o)     = r0;
        *reinterpret_cast<float4*>(out_acc + o + 4) = r1;
    }
}

extern "C" void kernel_launch(void* const* d_in, const int* in_sizes, int n_in,
                              void* d_out, int out_size, void* d_ws, size_t ws_size,
                              hipStream_t stream) {
    const float* embedding  = (const float*)d_in[0];
    const int*   edge_index = (const int*)d_in[1];
    const float* edge_attrs = (const float*)d_in[2];
    const int* from_ = edge_index;            // edge_index[0] = src
    const int* to_   = edge_index + N_EDGES;  // edge_index[1] = tgt

    float* out_emb0 = (float*)d_out;                                  // first half: emb0 copy (written by k_cvt)
    float* out_acc  = (float*)d_out + (size_t)N_NODES * EMB_DIM;      // second half: layer mean

    // workspace carve-up (~84 MB)
    char* ws = (char*)d_ws;
    size_t off = 0;
    auto alloc = [&](size_t bytes) -> void* {
        void* p = ws + off;
        off += (bytes + 255) & ~(size_t)255;
        return p;
    };
    uint4* emb0b   = (uint4*)alloc((size_t)N_NODES * 16 * sizeof(uint4));  // 25.6MB bf16
    uint4* e1b     = (uint4*)alloc((size_t)N_NODES * 16 * sizeof(uint4));  // 25.6MB bf16
    uint4* e2b     = (uint4*)alloc((size_t)N_NODES * 16 * sizeof(uint4));  // 25.6MB bf16
    float* sum_out = (float*)alloc(sizeof(float) * N_NODES);
    int*   deg     = (int*)  alloc(sizeof(int)   * N_NODES);
    int*   scanloc = (int*)  alloc(sizeof(int)   * N_NODES);
    int*   bsums   = (int*)  alloc(sizeof(int)   * SCAN_BLOCKS);
    int*   row_ptr = (int*)  alloc(sizeof(int)   * (N_NODES + 1));
    int*   cursor  = (int*)  alloc(sizeof(int)   * N_NODES);
    int2*  cv      = (int2*) alloc(sizeof(int2)  * N_EDGES);               // {col, val}

    const int nblk = SCAN_BLOCKS;                 // 391
    const int eblk = (N_EDGES + 255) / 256;       // 2344
    const int cblk = (N_NODES * EMB_DIM / 8 + 255) / 256;  // 6250
    const int sblk = (N_NODES * 16 + 255) / 256;  // 6250

    k_init<<<nblk, 256, 0, stream>>>(sum_out, deg);
    k_edge<<<eblk, 256, 0, stream>>>(to_, deg);
    k_scan1<<<nblk, 256, 0, stream>>>(deg, scanloc, bsums);
    k_scan2<<<1, 256, 0, stream>>>(bsums);
    k_scan3<<<nblk, 256, 0, stream>>>(scanloc, bsums, row_ptr, cursor);
    k_fill<<<eblk, 256, 0, stream>>>(from_, to_, edge_attrs, sum_out, cursor, cv);
    k_norm<<<nblk, 256, 0, stream>>>(row_ptr, cv, sum_out);
    k_cvt<<<cblk, 256, 0, stream>>>(embedding, emb0b, out_emb0);

    // layer 1: e1b = bf16(A @ emb0b)
    k_spmm<0><<<sblk, 256, 0, stream>>>(row_ptr, cv, emb0b, e1b,
                                        nullptr, nullptr, nullptr, nullptr);
    // layer 2: e2b = bf16(A @ e1b)
    k_spmm<0><<<sblk, 256, 0, stream>>>(row_ptr, cv, e1b, e2b,
                                        nullptr, nullptr, nullptr, nullptr);
    // layer 3 (fused): out_acc = (emb0 + e1b + e2b + A@e2b)*0.25
    k_spmm<1><<<sblk, 256, 0, stream>>>(row_ptr, cv, e2b, nullptr,
                                        embedding, e1b, e2b, out_acc);
}